// Round 1
// baseline (277.932 us; speedup 1.0000x reference)
//
#include <hip/hip_runtime.h>
#include <hip/hip_bf16.h>

// Output per (b, seg, np, chunk, p): 4x4 = mean over frames of [x;1][x;1]^T.
// 3 unique segment types (nb_fr = 136, 68, 45); out segs {0},{1,2},{3,4,5}.
// Input x: (256, 2048, 25, 3) f32, frame = 75 contiguous floats.
// Out: (256, 6, 5, 15, 5, 4, 4) f32.

__global__ __launch_bounds__(256) void gauss_kernel(const float* __restrict__ x,
                                                    float* __restrict__ out) {
    __shared__ float lds[2250];   // [250 threads][9 sums]
    __shared__ float red[225];    // [25 j][9 sums]
    __shared__ float outm[400];   // [25 j][16]

    int bid   = blockIdx.x;
    int chunk = bid % 15;
    int tmp   = bid / 15;
    int stype = tmp % 3;
    int b     = tmp / 3;

    const int nbs[3] = {136, 68, 45};
    int ns = nbs[stype];
    int f0 = chunk * ns;
    int f1 = (chunk == 14) ? 2048 : (f0 + ns);
    float inv_n = 1.0f / (float)(f1 - f0);

    int tid = threadIdx.x;
    if (tid < 250) {
        int j    = tid % 25;
        int tsub = tid / 25;
        const float* base = x + (size_t)b * (2048 * 75) + j * 3;
        float s0=0.f,s1=0.f,s2=0.f,s3=0.f,s4=0.f,s5=0.f,s6=0.f,s7=0.f,s8=0.f;
        for (int t = f0 + tsub; t < f1; t += 10) {
            const float* p = base + t * 75;
            float x0 = p[0], x1 = p[1], x2 = p[2];
            s0 += x0;     s1 += x1;     s2 += x2;
            s3 += x0*x0;  s4 += x0*x1;  s5 += x0*x2;
            s6 += x1*x1;  s7 += x1*x2;  s8 += x2*x2;
        }
        float* l = &lds[tid * 9];
        l[0]=s0; l[1]=s1; l[2]=s2; l[3]=s3; l[4]=s4; l[5]=s5; l[6]=s6; l[7]=s7; l[8]=s8;
    }
    __syncthreads();

    if (tid < 225) {
        int j = tid / 9, si = tid % 9;
        float v = 0.f;
        #pragma unroll
        for (int ts = 0; ts < 10; ++ts) v += lds[(ts * 25 + j) * 9 + si];
        red[j * 9 + si] = v;
    }
    __syncthreads();

    if (tid < 25) {
        const float* r = &red[tid * 9];
        float mu0 = r[0]*inv_n, mu1 = r[1]*inv_n, mu2 = r[2]*inv_n;
        float m00 = r[3]*inv_n, m01 = r[4]*inv_n, m02 = r[5]*inv_n;
        float m11 = r[6]*inv_n, m12 = r[7]*inv_n, m22 = r[8]*inv_n;
        float* o = &outm[tid * 16];
        o[0]=m00; o[1]=m01; o[2]=m02; o[3]=mu0;
        o[4]=m01; o[5]=m11; o[6]=m12; o[7]=mu1;
        o[8]=m02; o[9]=m12; o[10]=m22; o[11]=mu2;
        o[12]=mu0; o[13]=mu1; o[14]=mu2; o[15]=1.0f;
    }
    __syncthreads();

    // duplicate-aware write: stype0 -> seg 0; stype1 -> segs 1,2; stype2 -> segs 3,4,5
    int so0  = (stype == 0) ? 0 : (stype == 1) ? 1 : 3;
    int ndup = (stype == 0) ? 1 : (stype == 1) ? 2 : 3;
    int total = 400 * ndup;
    size_t obase = (size_t)b * 36000 + (size_t)chunk * 80;
    for (int idx = tid; idx < total; idx += 256) {
        int dup = idx / 400;
        int r   = idx % 400;
        int np  = r / 80;
        int rem = r % 80;  // p*16 + e, contiguous 80-float runs
        out[obase + (size_t)(so0 + dup) * 6000 + (size_t)np * 1200 + rem] = outm[r];
    }
}

extern "C" void kernel_launch(void* const* d_in, const int* in_sizes, int n_in,
                              void* d_out, int out_size, void* d_ws, size_t ws_size,
                              hipStream_t stream) {
    const float* x = (const float*)d_in[0];
    float* out = (float*)d_out;
    int blocks = 256 * 3 * 15;  // b * stype * chunk
    gauss_kernel<<<blocks, 256, 0, stream>>>(x, out);
}